// Round 5
// baseline (643.285 us; speedup 1.0000x reference)
//
#include <hip/hip_runtime.h>

// CRF forward (log partition), B=256, T=2048, N=64, MI355X.
//
// Round 5: round-4 chunked scan (4 waves x 16 basis columns = 64x64 chunk
// transfer matrix; psi-permuted A-fragments, zero-shuffle MFMA feedback) with
// the register/occupancy contract PINNED:
//   - amdgpu_waves_per_eu(4,4): compiler budget = 128 VGPR, occupancy = 4
//     waves/SIMD. Rounds 3/4 showed LLVM reg-minimizes toward max occupancy
//     (VGPR 120/56), sinking prefetch loads to their uses -> vmcnt stalls.
//   - eu ring is a 2-bank double buffer (4 steps/bank, refill-after-consume,
//     consumed 2 groups later -> 8-step prefetch distance, no ring copies).

typedef __attribute__((ext_vector_type(4))) float f32x4;
typedef __attribute__((ext_vector_type(8))) short bf16x8;

namespace {
constexpr int kB = 256;
constexpr int kT = 2048;
constexpr int kN = 64;
constexpr int kC = 8;        // chunks
constexpr int kL = kT / kC;  // 256 steps per chunk
constexpr int kStart = 1;    // GO
constexpr int kEnd = 2;      // EOS
constexpr long kTileFloats = (long)kB * kC * 4 * 1024;  // 8192 tiles x 64x16
constexpr long kNumTiles = (long)kB * kC * 4;
}  // namespace

// ---------- pre-pass: eu_sw[b][t][q4*16+mt*4+r] = bf16(exp(unary[b][t][mt*16+q4*4+r]))
// outStride = bytes per (b,t) row (128 packed, 256 in-place). May alias `in`:
// each row's 32 pairs are handled within one wave; loads of a row complete
// before its stores issue (per-lane data dep + lockstep program order).
__global__ void exp_swizzle_kernel(const float* in, char* outbase, int outStride) {
  const int total = kB * kT * 32;  // pairs
  int p = blockIdx.x * blockDim.x + threadIdx.x;
  const int stride = gridDim.x * blockDim.x;
  for (; p < total; p += stride) {
    const int r = p >> 5;
    const int j0 = (p & 31) << 1;
    const float2 v = *(const float2*)(in + (size_t)r * kN + j0);
    const float e0 = __expf(v.x), e1 = __expf(v.y);
    unsigned u0 = __float_as_uint(e0);
    u0 += 0x7FFFu + ((u0 >> 16) & 1u);  // RNE to bf16
    unsigned u1 = __float_as_uint(e1);
    u1 += 0x7FFFu + ((u1 >> 16) & 1u);
    const unsigned d = (u1 & 0xFFFF0000u) | (u0 >> 16);
    const int pi = ((j0 >> 2) & 3) * 16 + ((j0 >> 4) << 2) + (j0 & 3);
    *(unsigned*)(outbase + (size_t)r * outStride + pi * 2) = d;
  }
}

// ---------- helpers ----------
__device__ __forceinline__ unsigned pack2bf(float lo, float hi) {
  return __builtin_amdgcn_perm(__float_as_uint(hi), __float_as_uint(lo), 0x07060302u);
}

__device__ __forceinline__ bf16x8 pack_bfrag(f32x4 lo, f32x4 hi) {
  union { unsigned u[4]; bf16x8 s; } r;
  r.u[0] = pack2bf(lo.x, lo.y);
  r.u[1] = pack2bf(lo.z, lo.w);
  r.u[2] = pack2bf(hi.x, hi.y);
  r.u[3] = pack2bf(hi.z, hi.w);
  return r.s;
}

__device__ __forceinline__ f32x4 expand2(unsigned u, unsigned v) {
  f32x4 e;
  e.x = __uint_as_float(u << 16);
  e.y = __uint_as_float(u & 0xFFFF0000u);
  e.z = __uint_as_float(v << 16);
  e.w = __uint_as_float(v & 0xFFFF0000u);
  return e;
}

// One step: Q = E*Acc (8 MFMA), Acc' = Q .* eu_rows
__device__ __forceinline__ void crf_step(f32x4 (&ps)[4], const bf16x8 (&af)[4][2],
                                         uint4 u0, uint4 u1) {
  const f32x4 e0 = expand2(u0.x, u0.y);
  const f32x4 e1 = expand2(u0.z, u0.w);
  const f32x4 e2 = expand2(u1.x, u1.y);
  const f32x4 e3 = expand2(u1.z, u1.w);

  const bf16x8 b0 = pack_bfrag(ps[0], ps[1]);
  const bf16x8 b1 = pack_bfrag(ps[2], ps[3]);
  const f32x4 z4 = {0.f, 0.f, 0.f, 0.f};

  f32x4 q0 = __builtin_amdgcn_mfma_f32_16x16x32_bf16(af[0][0], b0, z4, 0, 0, 0);
  f32x4 q1 = __builtin_amdgcn_mfma_f32_16x16x32_bf16(af[1][0], b0, z4, 0, 0, 0);
  f32x4 q2 = __builtin_amdgcn_mfma_f32_16x16x32_bf16(af[2][0], b0, z4, 0, 0, 0);
  f32x4 q3 = __builtin_amdgcn_mfma_f32_16x16x32_bf16(af[3][0], b0, z4, 0, 0, 0);
  q0 = __builtin_amdgcn_mfma_f32_16x16x32_bf16(af[0][1], b1, q0, 0, 0, 0);
  q1 = __builtin_amdgcn_mfma_f32_16x16x32_bf16(af[1][1], b1, q1, 0, 0, 0);
  q2 = __builtin_amdgcn_mfma_f32_16x16x32_bf16(af[2][1], b1, q2, 0, 0, 0);
  q3 = __builtin_amdgcn_mfma_f32_16x16x32_bf16(af[3][1], b1, q3, 0, 0, 0);

  ps[0] = q0 * e0;
  ps[1] = q1 * e1;
  ps[2] = q2 * e2;
  ps[3] = q3 * e3;
}

// Per-wave renorm by exact power of 2 from lane 0's ps[0].x exponent.
// Tile spread bounded (~2^21); 4-step growth <= 2^56 -> max < 2^78, safe.
__device__ __forceinline__ void renorm(f32x4 (&ps)[4], float& tot_e) {
  const unsigned eref = __builtin_amdgcn_readfirstlane(__float_as_uint(ps[0].x));
  const int e = (int)((eref >> 23) & 0xFFu) - 127;
  const float sc = __uint_as_float((unsigned)(127 - e) << 23);
#pragma unroll
  for (int mt = 0; mt < 4; ++mt) ps[mt] *= sc;
  tot_e += (float)e;
}

__device__ __forceinline__ float exp2i(int d) {  // 2^d for d in [-126, 127]
  return (d <= -127) ? 0.f : __uint_as_float((unsigned)(127 + d) << 23);
}

// ---------- chunk kernel: 4 waves compute one chunk's 64x64 matrix ----------
__global__ __launch_bounds__(256)
__attribute__((amdgpu_waves_per_eu(4, 4))) void chunk_kernel(
    const char* __restrict__ eu, int euStride, const float* __restrict__ trans,
    const int* __restrict__ lengths, char* __restrict__ scr, int scrStride) {
  const int b = blockIdx.x >> 3;
  const int c = blockIdx.x & 7;
  const int w = threadIdx.x >> 6;
  const int lane = threadIdx.x & 63;
  const int col = lane & 15;
  const int q4 = lane >> 4;

  const int len = lengths[b];
  const int start = c * kL;
  if (start >= len) return;  // uniform per block; combine skips these chunks
  const int steps = (len - start < kL) ? (len - start) : kL;

  // Static A-fragments, psi-permuted K (verified rounds 2-4).
  bf16x8 af[4][2];
#pragma unroll
  for (int mt = 0; mt < 4; ++mt) {
#pragma unroll
    for (int kc = 0; kc < 2; ++kc) {
      union { unsigned u[4]; bf16x8 s; } fr;
#pragma unroll
      for (int jp = 0; jp < 4; ++jp) {
        const int j0 = 2 * jp, j1 = 2 * jp + 1;
        const int k0 = (2 * kc + (j0 >> 2)) * 16 + q4 * 4 + (j0 & 3);
        const int k1 = (2 * kc + (j1 >> 2)) * 16 + q4 * 4 + (j1 & 3);
        unsigned e0 = __float_as_uint(__expf(trans[(mt * 16 + col) * kN + k0])) + 0x8000u;
        unsigned e1 = __float_as_uint(__expf(trans[(mt * 16 + col) * kN + k1])) + 0x8000u;
        fr.u[jp] = __builtin_amdgcn_perm(e1, e0, 0x07060302u);
      }
      af[mt][kc] = fr.s;
    }
  }

  // Acc = identity columns: this wave owns columns w*16..w*16+15.
  const int mycol = w * 16 + col;
  f32x4 ps[4];
#pragma unroll
  for (int mt = 0; mt < 4; ++mt) {
    const int rb = mt * 16 + q4 * 4;
    f32x4 v;
    v.x = (rb + 0 == mycol) ? 1.f : 0.f;
    v.y = (rb + 1 == mycol) ? 1.f : 0.f;
    v.z = (rb + 2 == mycol) ? 1.f : 0.f;
    v.w = (rb + 3 == mycol) ? 1.f : 0.f;
    ps[mt] = v;
  }

  // eu double buffer: 2 banks x 4 steps x 8 dwords (32 B/step/lane).
  // Bank is refilled right after being consumed and consumed again 2 groups
  // later -> 8-step issue-to-use distance.
  const char* ebase = eu + ((size_t)b * kT + start) * (size_t)euStride + q4 * 32;
  uint4 bk0[4][2], bk1[4][2];
#pragma unroll
  for (int i = 0; i < 4; ++i) {
    bk0[i][0] = *(const uint4*)(ebase + (size_t)i * euStride);
    bk0[i][1] = *(const uint4*)(ebase + (size_t)i * euStride + 16);
  }
#pragma unroll
  for (int i = 0; i < 4; ++i) {
    bk1[i][0] = *(const uint4*)(ebase + (size_t)(4 + i) * euStride);
    bk1[i][1] = *(const uint4*)(ebase + (size_t)(4 + i) * euStride + 16);
  }
  int pfRel = 8;
  const int pfRelMax = kL - 4;  // rows start..start+kL-1 always valid memory
  float tot_e = 0.0f;

  const int G = steps >> 2;  // full 4-step groups
  int grp = 0;
  for (; grp + 2 <= G; grp += 2) {
    // ---- group grp: consume bank0, then refill it for grp+2 ----
    crf_step(ps, af, bk0[0][0], bk0[0][1]);
    crf_step(ps, af, bk0[1][0], bk0[1][1]);
    crf_step(ps, af, bk0[2][0], bk0[2][1]);
    crf_step(ps, af, bk0[3][0], bk0[3][1]);
    renorm(ps, tot_e);
    {
      const char* pf = ebase + (size_t)pfRel * euStride;
#pragma unroll
      for (int i = 0; i < 4; ++i) {
        bk0[i][0] = *(const uint4*)(pf + (size_t)i * euStride);
        bk0[i][1] = *(const uint4*)(pf + (size_t)i * euStride + 16);
      }
      pfRel += 4;
      if (pfRel > pfRelMax) pfRel = pfRelMax;
    }
    // ---- group grp+1: consume bank1, then refill it for grp+3 ----
    crf_step(ps, af, bk1[0][0], bk1[0][1]);
    crf_step(ps, af, bk1[1][0], bk1[1][1]);
    crf_step(ps, af, bk1[2][0], bk1[2][1]);
    crf_step(ps, af, bk1[3][0], bk1[3][1]);
    renorm(ps, tot_e);
    {
      const char* pf = ebase + (size_t)pfRel * euStride;
#pragma unroll
      for (int i = 0; i < 4; ++i) {
        bk1[i][0] = *(const uint4*)(pf + (size_t)i * euStride);
        bk1[i][1] = *(const uint4*)(pf + (size_t)i * euStride + 16);
      }
      pfRel += 4;
      if (pfRel > pfRelMax) pfRel = pfRelMax;
    }
  }
  // Bank state here: bank0 holds group (grp), bank1 holds group (grp+1).
  const int pr = steps & 3;
  if (grp < G) {  // G odd: one last full group from bank0, partial from bank1
    crf_step(ps, af, bk0[0][0], bk0[0][1]);
    crf_step(ps, af, bk0[1][0], bk0[1][1]);
    crf_step(ps, af, bk0[2][0], bk0[2][1]);
    crf_step(ps, af, bk0[3][0], bk0[3][1]);
    renorm(ps, tot_e);
    if (pr > 0) crf_step(ps, af, bk1[0][0], bk1[0][1]);
    if (pr > 1) crf_step(ps, af, bk1[1][0], bk1[1][1]);
    if (pr > 2) crf_step(ps, af, bk1[2][0], bk1[2][1]);
  } else {  // G even: partial from bank0
    if (pr > 0) crf_step(ps, af, bk0[0][0], bk0[0][1]);
    if (pr > 1) crf_step(ps, af, bk0[1][0], bk0[1][1]);
    if (pr > 2) crf_step(ps, af, bk0[2][0], bk0[2][1]);
  }

  // Store 64x16 tile, column-major flat index F = tile*1024 + col*64 + row,
  // mapped to scratch slots of 32 floats with byte stride scrStride.
  const long tileIdx = ((long)b * kC + c) * 4 + w;
#pragma unroll
  for (int mt = 0; mt < 4; ++mt) {
    const long slot = tileIdx * 32 + col * 2 + (mt >> 1);
    char* addr = scr + slot * (long)scrStride + ((mt & 1) * 16 + q4 * 4) * 4;
    *(f32x4*)addr = ps[mt];
  }
  if (lane == 0) {
    const long F = kTileFloats + tileIdx;
    *(float*)(scr + (F >> 5) * (long)scrStride + (F & 31) * 4) = tot_e;
  }
}

// ---------- combine: per batch, chain the chunk matrices (one wave) ----------
__global__ __launch_bounds__(64) void combine_kernel(
    const char* __restrict__ scr, int scrStride, const float* __restrict__ trans,
    const int* __restrict__ lengths, float* __restrict__ out) {
  const int b = blockIdx.x;
  const int j = threadIdx.x;
  const int len = lengths[b];

#define LDS_SCR(F) (*(const float*)(scr + ((long)(F) >> 5) * (long)scrStride + ((F) & 31) * 4))

  // alpha after chunk 0 = column kStart of chunk-0 matrix (wave 0's tile).
  const long t0 = (long)b * kC * 4;
  float a = LDS_SCR(t0 * 1024 + kStart * 64 + j);
  float totE = LDS_SCR(kTileFloats + t0);

  for (int c = 1; c < kC; ++c) {
    if (c * kL >= len) break;  // chunks are contiguous-active
    const long tb = ((long)b * kC + c) * 4;
    float s0 = 0.f, s1 = 0.f, s2 = 0.f, s3 = 0.f;
#pragma unroll
    for (int k16 = 0; k16 < 16; ++k16) {
      const float a0 = __int_as_float(__builtin_amdgcn_readlane(__float_as_int(a), k16));
      const float a1 = __int_as_float(__builtin_amdgcn_readlane(__float_as_int(a), 16 + k16));
      const float a2 = __int_as_float(__builtin_amdgcn_readlane(__float_as_int(a), 32 + k16));
      const float a3 = __int_as_float(__builtin_amdgcn_readlane(__float_as_int(a), 48 + k16));
      s0 = fmaf(LDS_SCR((tb + 0) * 1024 + k16 * 64 + j), a0, s0);
      s1 = fmaf(LDS_SCR((tb + 1) * 1024 + k16 * 64 + j), a1, s1);
      s2 = fmaf(LDS_SCR((tb + 2) * 1024 + k16 * 64 + j), a2, s2);
      s3 = fmaf(LDS_SCR((tb + 3) * 1024 + k16 * 64 + j), a3, s3);
    }
    const float e0 = LDS_SCR(kTileFloats + tb + 0);
    const float e1 = LDS_SCR(kTileFloats + tb + 1);
    const float e2 = LDS_SCR(kTileFloats + tb + 2);
    const float e3 = LDS_SCR(kTileFloats + tb + 3);
    const float em = fmaxf(fmaxf(e0, e1), fmaxf(e2, e3));
    a = s0 * exp2i((int)(e0 - em)) + s1 * exp2i((int)(e1 - em)) +
        s2 * exp2i((int)(e2 - em)) + s3 * exp2i((int)(e3 - em));
    totE += em;

    // renorm alpha (exact power of 2 from the wave max)
    float m = a;
#pragma unroll
    for (int mask = 1; mask < 64; mask <<= 1) m = fmaxf(m, __shfl_xor(m, mask));
    const int e = (int)((__float_as_uint(m) >> 23) & 0xFFu) - 127;
    a *= exp2i(-e);
    totE += (float)e;
  }

  float term = a * __expf(trans[kEnd * kN + j]);
#pragma unroll
  for (int mask = 1; mask < 64; mask <<= 1) term += __shfl_xor(term, mask);

  if (j == 0) out[b] = totE * 0.69314718055994530942f + logf(term);
#undef LDS_SCR
}

extern "C" void kernel_launch(void* const* d_in, const int* in_sizes, int n_in,
                              void* d_out, int out_size, void* d_ws, size_t ws_size,
                              hipStream_t stream) {
  const float* unary = (const float*)d_in[0];  // [B, T, N] fp32, 128 MiB
  const float* trans = (const float*)d_in[1];  // [N, N] fp32
  const int* lengths = (const int*)d_in[2];    // [B] int32
  float* out = (float*)d_out;                  // [B] fp32

  const size_t euBytes = (size_t)kB * kT * kN * 2;                // 64 MiB
  const size_t scrBytes = (size_t)(kTileFloats + kNumTiles) * 4;  // ~33.6 MB

  char* euB;
  int euS;
  char* scrB;
  int scrS;
  if (ws_size >= euBytes + scrBytes) {
    euB = (char*)d_ws;
    euS = 128;
    scrB = (char*)d_ws + euBytes;
    scrS = 128;
  } else if (ws_size >= scrBytes) {
    euB = (char*)d_in[0];
    euS = 256;
    scrB = (char*)d_ws;
    scrS = 128;
  } else {
    // Everything in-place over d_in[0]: eu in lower 128 B of each 256-B row,
    // tiles/exps in upper halves (disjoint; harness restores inputs).
    euB = (char*)d_in[0];
    euS = 256;
    scrB = (char*)d_in[0] + 128;
    scrS = 256;
  }

  exp_swizzle_kernel<<<dim3(4096), dim3(256), 0, stream>>>(unary, euB, euS);
  chunk_kernel<<<dim3(kB * kC), dim3(256), 0, stream>>>(euB, euS, trans, lengths,
                                                        scrB, scrS);
  combine_kernel<<<dim3(kB), dim3(64), 0, stream>>>(scrB, scrS, trans, lengths, out);
}

// Round 6
// 512.044 us; speedup vs baseline: 1.2563x; 1.2563x over previous
//
#include <hip/hip_runtime.h>

// CRF forward (log partition), B=256, T=2048, N=64, MI355X.
//
// Round 6: chunked scan (C=8, 4 waves x 16 basis columns per chunk; psi-
// permuted A-fragments, zero-shuffle MFMA feedback) with eu staged through an
// LDS DOUBLE BUFFER instead of a register ring. Rounds 3-5 proved the
// compiler defeats register-resident prefetch (sinks loads at VGPR 56/120,
// spills at a forced budget: r5 WRITE_SIZE 328 MB). LDS staging is immune:
// per stage (32 steps) each thread does one dwordx4 global load issued at
// stage start (a full stage in flight) + one ds_write right before the
// barrier; per step each lane does 2x ds_read_b128 (broadcast across its
// 16-lane group, conflict-free). VGPR stays ~64 -> full co-residency
// (2048 blocks x 8 KiB LDS = 8 blocks/CU in one shot).

typedef __attribute__((ext_vector_type(4))) float f32x4;
typedef __attribute__((ext_vector_type(8))) short bf16x8;

namespace {
constexpr int kB = 256;
constexpr int kT = 2048;
constexpr int kN = 64;
constexpr int kC = 8;        // chunks
constexpr int kL = kT / kC;  // 256 steps per chunk
constexpr int kStart = 1;    // GO
constexpr int kEnd = 2;      // EOS
constexpr long kTileFloats = (long)kB * kC * 4 * 1024;  // 8192 tiles x 64x16
constexpr long kNumTiles = (long)kB * kC * 4;
}  // namespace

// ---------- pre-pass: eu_sw[b][t][q4*16+mt*4+r] = bf16(exp(unary[b][t][mt*16+q4*4+r]))
// outStride = bytes per (b,t) row (128 packed, 256 in-place). May alias `in`:
// each row's pairs are handled within one wave; loads of a row complete
// before its stores issue (per-lane data dep + lockstep program order).
__global__ void exp_swizzle_kernel(const float* in, char* outbase, int outStride) {
  const int total = kB * kT * 32;  // pairs
  int p = blockIdx.x * blockDim.x + threadIdx.x;
  const int stride = gridDim.x * blockDim.x;
  for (; p < total; p += stride) {
    const int r = p >> 5;
    const int j0 = (p & 31) << 1;
    const float2 v = *(const float2*)(in + (size_t)r * kN + j0);
    const float e0 = __expf(v.x), e1 = __expf(v.y);
    unsigned u0 = __float_as_uint(e0);
    u0 += 0x7FFFu + ((u0 >> 16) & 1u);  // RNE to bf16
    unsigned u1 = __float_as_uint(e1);
    u1 += 0x7FFFu + ((u1 >> 16) & 1u);
    const unsigned d = (u1 & 0xFFFF0000u) | (u0 >> 16);
    const int pi = ((j0 >> 2) & 3) * 16 + ((j0 >> 4) << 2) + (j0 & 3);
    *(unsigned*)(outbase + (size_t)r * outStride + pi * 2) = d;
  }
}

// ---------- helpers ----------
__device__ __forceinline__ unsigned pack2bf(float lo, float hi) {
  return __builtin_amdgcn_perm(__float_as_uint(hi), __float_as_uint(lo), 0x07060302u);
}

__device__ __forceinline__ bf16x8 pack_bfrag(f32x4 lo, f32x4 hi) {
  union { unsigned u[4]; bf16x8 s; } r;
  r.u[0] = pack2bf(lo.x, lo.y);
  r.u[1] = pack2bf(lo.z, lo.w);
  r.u[2] = pack2bf(hi.x, hi.y);
  r.u[3] = pack2bf(hi.z, hi.w);
  return r.s;
}

__device__ __forceinline__ f32x4 expand2(unsigned u, unsigned v) {
  f32x4 e;
  e.x = __uint_as_float(u << 16);
  e.y = __uint_as_float(u & 0xFFFF0000u);
  e.z = __uint_as_float(v << 16);
  e.w = __uint_as_float(v & 0xFFFF0000u);
  return e;
}

// One step: Q = E*Acc (8 MFMA), Acc' = Q .* eu_rows
__device__ __forceinline__ void crf_step(f32x4 (&ps)[4], const bf16x8 (&af)[4][2],
                                         uint4 u0, uint4 u1) {
  const f32x4 e0 = expand2(u0.x, u0.y);
  const f32x4 e1 = expand2(u0.z, u0.w);
  const f32x4 e2 = expand2(u1.x, u1.y);
  const f32x4 e3 = expand2(u1.z, u1.w);

  const bf16x8 b0 = pack_bfrag(ps[0], ps[1]);
  const bf16x8 b1 = pack_bfrag(ps[2], ps[3]);
  const f32x4 z4 = {0.f, 0.f, 0.f, 0.f};

  f32x4 q0 = __builtin_amdgcn_mfma_f32_16x16x32_bf16(af[0][0], b0, z4, 0, 0, 0);
  f32x4 q1 = __builtin_amdgcn_mfma_f32_16x16x32_bf16(af[1][0], b0, z4, 0, 0, 0);
  f32x4 q2 = __builtin_amdgcn_mfma_f32_16x16x32_bf16(af[2][0], b0, z4, 0, 0, 0);
  f32x4 q3 = __builtin_amdgcn_mfma_f32_16x16x32_bf16(af[3][0], b0, z4, 0, 0, 0);
  q0 = __builtin_amdgcn_mfma_f32_16x16x32_bf16(af[0][1], b1, q0, 0, 0, 0);
  q1 = __builtin_amdgcn_mfma_f32_16x16x32_bf16(af[1][1], b1, q1, 0, 0, 0);
  q2 = __builtin_amdgcn_mfma_f32_16x16x32_bf16(af[2][1], b1, q2, 0, 0, 0);
  q3 = __builtin_amdgcn_mfma_f32_16x16x32_bf16(af[3][1], b1, q3, 0, 0, 0);

  ps[0] = q0 * e0;
  ps[1] = q1 * e1;
  ps[2] = q2 * e2;
  ps[3] = q3 * e3;
}

// Per-wave renorm by exact power of 2 from lane 0's ps[0].x exponent.
// Tile spread bounded (~2^21); 4-step growth <= 2^56 -> max < 2^78, safe.
__device__ __forceinline__ void renorm(f32x4 (&ps)[4], float& tot_e) {
  const unsigned eref = __builtin_amdgcn_readfirstlane(__float_as_uint(ps[0].x));
  const int e = (int)((eref >> 23) & 0xFFu) - 127;
  const float sc = __uint_as_float((unsigned)(127 - e) << 23);
#pragma unroll
  for (int mt = 0; mt < 4; ++mt) ps[mt] *= sc;
  tot_e += (float)e;
}

__device__ __forceinline__ float exp2i(int d) {  // 2^d for d in [-126, 127]
  return (d <= -127) ? 0.f : __uint_as_float((unsigned)(127 + d) << 23);
}

// ---------- chunk kernel: 4 waves compute one chunk's 64x64 matrix ----------
__global__ __launch_bounds__(256) void chunk_kernel(
    const char* __restrict__ eu, int euStride, const float* __restrict__ trans,
    const int* __restrict__ lengths, char* __restrict__ scr, int scrStride) {
  const int b = blockIdx.x >> 3;
  const int c = blockIdx.x & 7;
  const int tid = threadIdx.x;
  const int w = tid >> 6;
  const int lane = tid & 63;
  const int col = lane & 15;
  const int q4 = lane >> 4;

  const int len = lengths[b];
  const int start = c * kL;
  if (start >= len) return;  // block-uniform exit (before any barrier)
  const int steps = (len - start < kL) ? (len - start) : kL;

  __shared__ __align__(16) char smem[2][4096];  // 2 x 32 steps x 128 B

  // Static A-fragments, psi-permuted K (verified rounds 2-5).
  bf16x8 af[4][2];
#pragma unroll
  for (int mt = 0; mt < 4; ++mt) {
#pragma unroll
    for (int kc = 0; kc < 2; ++kc) {
      union { unsigned u[4]; bf16x8 s; } fr;
#pragma unroll
      for (int jp = 0; jp < 4; ++jp) {
        const int j0 = 2 * jp, j1 = 2 * jp + 1;
        const int k0 = (2 * kc + (j0 >> 2)) * 16 + q4 * 4 + (j0 & 3);
        const int k1 = (2 * kc + (j1 >> 2)) * 16 + q4 * 4 + (j1 & 3);
        unsigned e0 = __float_as_uint(__expf(trans[(mt * 16 + col) * kN + k0])) + 0x8000u;
        unsigned e1 = __float_as_uint(__expf(trans[(mt * 16 + col) * kN + k1])) + 0x8000u;
        fr.u[jp] = __builtin_amdgcn_perm(e1, e0, 0x07060302u);
      }
      af[mt][kc] = fr.s;
    }
  }

  // Acc = identity columns: this wave owns columns w*16..w*16+15.
  const int mycol = w * 16 + col;
  f32x4 ps[4];
#pragma unroll
  for (int mt = 0; mt < 4; ++mt) {
    const int rb = mt * 16 + q4 * 4;
    f32x4 v;
    v.x = (rb + 0 == mycol) ? 1.f : 0.f;
    v.y = (rb + 1 == mycol) ? 1.f : 0.f;
    v.z = (rb + 2 == mycol) ? 1.f : 0.f;
    v.w = (rb + 3 == mycol) ? 1.f : 0.f;
    ps[mt] = v;
  }

  // Staging: thread tid covers (row = tid>>3, 16-B segment = tid&7) of a
  // 32-row stage. LDS layout: row-major, 128 B/row (matches the swizzled
  // packed eu row), so lds offset = tid*16.
  const char* gblk = eu + ((size_t)b * kT + start) * (size_t)euStride;
  const size_t gthr = (size_t)(tid >> 3) * euStride + (tid & 7) * 16;
  const int S = (steps + 31) >> 5;  // stages (block-uniform)

  // Preamble: stage 0 into buf0.
  {
    const uint4 v = *(const uint4*)(gblk + gthr);
    *(uint4*)(smem[0] + tid * 16) = v;
  }
  __syncthreads();

  float tot_e = 0.0f;
  for (int s = 0; s < S; ++s) {
    // Issue next stage's global load at stage START (a full stage in flight
    // before its ds_write; barrier then has no outstanding vmem).
    uint4 v;
    const bool more = (s + 1 < S);
    if (more) v = *(const uint4*)(gblk + ((size_t)(s + 1) << 5) * euStride + gthr);

    const int ns = (steps - (s << 5) < 32) ? (steps - (s << 5)) : 32;
    const uint4* lb = (const uint4*)(smem[s & 1]) + q4 * 2;  // row stride 8 uint4
    const int g4 = ns >> 2;
    for (int g = 0; g < g4; ++g) {
      const uint4* p = lb + g * 32;
      crf_step(ps, af, p[0], p[1]);
      crf_step(ps, af, p[8], p[9]);
      crf_step(ps, af, p[16], p[17]);
      crf_step(ps, af, p[24], p[25]);
      renorm(ps, tot_e);
    }
    const int pr = ns & 3;
    if (pr) {
      const uint4* p = lb + g4 * 32;
      crf_step(ps, af, p[0], p[1]);
      if (pr > 1) crf_step(ps, af, p[8], p[9]);
      if (pr > 2) crf_step(ps, af, p[16], p[17]);
    }

    if (more) *(uint4*)(smem[(s + 1) & 1] + tid * 16) = v;
    __syncthreads();
  }

  // Store 64x16 tile, column-major flat index F = tile*1024 + col*64 + row,
  // mapped to scratch slots of 32 floats with byte stride scrStride.
  const long tileIdx = ((long)b * kC + c) * 4 + w;
#pragma unroll
  for (int mt = 0; mt < 4; ++mt) {
    const long slot = tileIdx * 32 + col * 2 + (mt >> 1);
    char* addr = scr + slot * (long)scrStride + ((mt & 1) * 16 + q4 * 4) * 4;
    *(f32x4*)addr = ps[mt];
  }
  if (lane == 0) {
    const long F = kTileFloats + tileIdx;
    *(float*)(scr + (F >> 5) * (long)scrStride + (F & 31) * 4) = tot_e;
  }
}

// ---------- combine: per batch, chain the chunk matrices (one wave) ----------
__global__ __launch_bounds__(64) void combine_kernel(
    const char* __restrict__ scr, int scrStride, const float* __restrict__ trans,
    const int* __restrict__ lengths, float* __restrict__ out) {
  const int b = blockIdx.x;
  const int j = threadIdx.x;
  const int len = lengths[b];

#define LDS_SCR(F) (*(const float*)(scr + ((long)(F) >> 5) * (long)scrStride + ((F) & 31) * 4))

  // alpha after chunk 0 = column kStart of chunk-0 matrix (wave 0's tile).
  const long t0 = (long)b * kC * 4;
  float a = LDS_SCR(t0 * 1024 + kStart * 64 + j);
  float totE = LDS_SCR(kTileFloats + t0);

  for (int c = 1; c < kC; ++c) {
    if (c * kL >= len) break;  // chunks are contiguous-active
    const long tb = ((long)b * kC + c) * 4;
    float s0 = 0.f, s1 = 0.f, s2 = 0.f, s3 = 0.f;
#pragma unroll
    for (int k16 = 0; k16 < 16; ++k16) {
      const float a0 = __int_as_float(__builtin_amdgcn_readlane(__float_as_int(a), k16));
      const float a1 = __int_as_float(__builtin_amdgcn_readlane(__float_as_int(a), 16 + k16));
      const float a2 = __int_as_float(__builtin_amdgcn_readlane(__float_as_int(a), 32 + k16));
      const float a3 = __int_as_float(__builtin_amdgcn_readlane(__float_as_int(a), 48 + k16));
      s0 = fmaf(LDS_SCR((tb + 0) * 1024 + k16 * 64 + j), a0, s0);
      s1 = fmaf(LDS_SCR((tb + 1) * 1024 + k16 * 64 + j), a1, s1);
      s2 = fmaf(LDS_SCR((tb + 2) * 1024 + k16 * 64 + j), a2, s2);
      s3 = fmaf(LDS_SCR((tb + 3) * 1024 + k16 * 64 + j), a3, s3);
    }
    const float e0 = LDS_SCR(kTileFloats + tb + 0);
    const float e1 = LDS_SCR(kTileFloats + tb + 1);
    const float e2 = LDS_SCR(kTileFloats + tb + 2);
    const float e3 = LDS_SCR(kTileFloats + tb + 3);
    const float em = fmaxf(fmaxf(e0, e1), fmaxf(e2, e3));
    a = s0 * exp2i((int)(e0 - em)) + s1 * exp2i((int)(e1 - em)) +
        s2 * exp2i((int)(e2 - em)) + s3 * exp2i((int)(e3 - em));
    totE += em;

    // renorm alpha (exact power of 2 from the wave max)
    float m = a;
#pragma unroll
    for (int mask = 1; mask < 64; mask <<= 1) m = fmaxf(m, __shfl_xor(m, mask));
    const int e = (int)((__float_as_uint(m) >> 23) & 0xFFu) - 127;
    a *= exp2i(-e);
    totE += (float)e;
  }

  float term = a * __expf(trans[kEnd * kN + j]);
#pragma unroll
  for (int mask = 1; mask < 64; mask <<= 1) term += __shfl_xor(term, mask);

  if (j == 0) out[b] = totE * 0.69314718055994530942f + logf(term);
#undef LDS_SCR
}

extern "C" void kernel_launch(void* const* d_in, const int* in_sizes, int n_in,
                              void* d_out, int out_size, void* d_ws, size_t ws_size,
                              hipStream_t stream) {
  const float* unary = (const float*)d_in[0];  // [B, T, N] fp32, 128 MiB
  const float* trans = (const float*)d_in[1];  // [N, N] fp32
  const int* lengths = (const int*)d_in[2];    // [B] int32
  float* out = (float*)d_out;                  // [B] fp32

  const size_t euBytes = (size_t)kB * kT * kN * 2;                // 64 MiB
  const size_t scrBytes = (size_t)(kTileFloats + kNumTiles) * 4;  // ~33.6 MB

  char* euB;
  int euS;
  char* scrB;
  int scrS;
  if (ws_size >= euBytes + scrBytes) {
    euB = (char*)d_ws;
    euS = 128;
    scrB = (char*)d_ws + euBytes;
    scrS = 128;
  } else if (ws_size >= scrBytes) {
    euB = (char*)d_in[0];
    euS = 256;
    scrB = (char*)d_ws;
    scrS = 128;
  } else {
    // Everything in-place over d_in[0]: eu in lower 128 B of each 256-B row,
    // tiles/exps in upper halves (disjoint; harness restores inputs).
    euB = (char*)d_in[0];
    euS = 256;
    scrB = (char*)d_in[0] + 128;
    scrS = 256;
  }

  exp_swizzle_kernel<<<dim3(4096), dim3(256), 0, stream>>>(unary, euB, euS);
  chunk_kernel<<<dim3(kB * kC), dim3(256), 0, stream>>>(euB, euS, trans, lengths,
                                                        scrB, scrS);
  combine_kernel<<<dim3(kB), dim3(64), 0, stream>>>(scrB, scrS, trans, lengths, out);
}

// Round 7
// 465.370 us; speedup vs baseline: 1.3823x; 1.1003x over previous
//
#include <hip/hip_runtime.h>

// CRF forward (log partition), B=256, T=2048, N=64, MI355X.
//
// Round 7: chunked scan (C=8, 4 waves x 16 basis columns per chunk matrix;
// psi-permuted A-fragments, zero-shuffle MFMA feedback). Changes vs r6:
//  - 512-thread blocks carry TWO chunks (grid 1024): doubles waves/CU if a
//    blocks/CU cap was limiting residency (r4/r6 both showed ~24% occupancy).
//  - eu staged as F32 (swizzled in-place by the pre-pass): no bf16->f32
//    expand in the step (-16 VALU/step).
//  - Fully unrolled 32-step stage body with immediate-offset ds_read_b128:
//    no address VALU, loads hoisted by the scheduler.
//  - Fixed 8-stage barrier cadence per block (halves with short/empty chunks
//    just barrier through) keeps block-level control flow uniform.

typedef __attribute__((ext_vector_type(4))) float f32x4;
typedef __attribute__((ext_vector_type(8))) short bf16x8;

namespace {
constexpr int kB = 256;
constexpr int kT = 2048;
constexpr int kN = 64;
constexpr int kC = 8;        // chunks
constexpr int kL = kT / kC;  // 256 steps per chunk
constexpr int kStart = 1;    // GO
constexpr int kEnd = 2;      // EOS
constexpr long kTileFloats = (long)kB * kC * 4 * 1024;  // 8192 tiles x 64x16
constexpr long kNumTiles = (long)kB * kC * 4;
}  // namespace

// ---------- pre-pass A (primary): in-place f32 row swizzle + exp ----------
// buf rows of 64 f32; within each row: out[pi(j)] = exp(in[j]),
// pi = ((j>>2)&3)*16 + ((j>>4)<<2) + (j&3). Row handled entirely within one
// wave (32 threads x 2 elems); loads complete before stores (lockstep).
__global__ void exp_swizzle_f32(float* buf) {
  const int total = kB * kT * 32;  // pairs
  int p = blockIdx.x * blockDim.x + threadIdx.x;
  const int stride = gridDim.x * blockDim.x;
  for (; p < total; p += stride) {
    const int r = p >> 5;
    const int j0 = (p & 31) << 1;
    float* row = buf + (size_t)r * kN;
    const float2 v = *(const float2*)(row + j0);
    const int pi = ((j0 >> 2) & 3) * 16 + ((j0 >> 4) << 2) + (j0 & 3);
    float2 o;
    o.x = __expf(v.x);
    o.y = __expf(v.y);
    *(float2*)(row + pi) = o;
  }
}

// ---------- pre-pass B (fallback): bf16 packed into lower 128 B of rows ----
__global__ void exp_swizzle_bf16(const float* in, char* outbase) {
  const int total = kB * kT * 32;  // pairs
  int p = blockIdx.x * blockDim.x + threadIdx.x;
  const int stride = gridDim.x * blockDim.x;
  for (; p < total; p += stride) {
    const int r = p >> 5;
    const int j0 = (p & 31) << 1;
    const float2 v = *(const float2*)(in + (size_t)r * kN + j0);
    const float e0 = __expf(v.x), e1 = __expf(v.y);
    unsigned u0 = __float_as_uint(e0);
    u0 += 0x7FFFu + ((u0 >> 16) & 1u);  // RNE to bf16
    unsigned u1 = __float_as_uint(e1);
    u1 += 0x7FFFu + ((u1 >> 16) & 1u);
    const unsigned d = (u1 & 0xFFFF0000u) | (u0 >> 16);
    const int pi = ((j0 >> 2) & 3) * 16 + ((j0 >> 4) << 2) + (j0 & 3);
    *(unsigned*)(outbase + (size_t)r * 256 + pi * 2) = d;
  }
}

// ---------- helpers ----------
__device__ __forceinline__ unsigned pack2bf(float lo, float hi) {
  return __builtin_amdgcn_perm(__float_as_uint(hi), __float_as_uint(lo), 0x07060302u);
}

__device__ __forceinline__ f32x4 expand2(unsigned u, unsigned v) {
  f32x4 e;
  e.x = __uint_as_float(u << 16);
  e.y = __uint_as_float(u & 0xFFFF0000u);
  e.z = __uint_as_float(v << 16);
  e.w = __uint_as_float(v & 0xFFFF0000u);
  return e;
}

// One step: Q = E*Acc (8 MFMA), Acc' = Q .* e. e read from LDS row `lrow`.
template <bool F32>
__device__ __forceinline__ void step_lds(f32x4 (&ps)[4], const bf16x8 (&af)[4][2],
                                         const char* lrow) {
  f32x4 e0, e1, e2, e3;
  if constexpr (F32) {
    e0 = *(const f32x4*)(lrow + 0);
    e1 = *(const f32x4*)(lrow + 16);
    e2 = *(const f32x4*)(lrow + 32);
    e3 = *(const f32x4*)(lrow + 48);
  } else {
    const uint4 u0 = *(const uint4*)(lrow + 0);
    const uint4 u1 = *(const uint4*)(lrow + 16);
    e0 = expand2(u0.x, u0.y);
    e1 = expand2(u0.z, u0.w);
    e2 = expand2(u1.x, u1.y);
    e3 = expand2(u1.z, u1.w);
  }

  union { unsigned u[4]; bf16x8 s; } b0u, b1u;
  b0u.u[0] = pack2bf(ps[0].x, ps[0].y);
  b0u.u[1] = pack2bf(ps[0].z, ps[0].w);
  b0u.u[2] = pack2bf(ps[1].x, ps[1].y);
  b0u.u[3] = pack2bf(ps[1].z, ps[1].w);
  const bf16x8 b0 = b0u.s;
  const f32x4 z4 = {0.f, 0.f, 0.f, 0.f};
  f32x4 q0 = __builtin_amdgcn_mfma_f32_16x16x32_bf16(af[0][0], b0, z4, 0, 0, 0);
  f32x4 q1 = __builtin_amdgcn_mfma_f32_16x16x32_bf16(af[1][0], b0, z4, 0, 0, 0);
  f32x4 q2 = __builtin_amdgcn_mfma_f32_16x16x32_bf16(af[2][0], b0, z4, 0, 0, 0);
  f32x4 q3 = __builtin_amdgcn_mfma_f32_16x16x32_bf16(af[3][0], b0, z4, 0, 0, 0);
  b1u.u[0] = pack2bf(ps[2].x, ps[2].y);
  b1u.u[1] = pack2bf(ps[2].z, ps[2].w);
  b1u.u[2] = pack2bf(ps[3].x, ps[3].y);
  b1u.u[3] = pack2bf(ps[3].z, ps[3].w);
  const bf16x8 b1 = b1u.s;
  q0 = __builtin_amdgcn_mfma_f32_16x16x32_bf16(af[0][1], b1, q0, 0, 0, 0);
  q1 = __builtin_amdgcn_mfma_f32_16x16x32_bf16(af[1][1], b1, q1, 0, 0, 0);
  q2 = __builtin_amdgcn_mfma_f32_16x16x32_bf16(af[2][1], b1, q2, 0, 0, 0);
  q3 = __builtin_amdgcn_mfma_f32_16x16x32_bf16(af[3][1], b1, q3, 0, 0, 0);

  ps[0] = q0 * e0;
  ps[1] = q1 * e1;
  ps[2] = q2 * e2;
  ps[3] = q3 * e3;
}

// Per-wave renorm by exact power of 2 from lane 0's ps[0].x exponent.
// Spread bounded (~2^21); 4-step growth <= 2^56 -> max < 2^78, safe.
__device__ __forceinline__ void renorm(f32x4 (&ps)[4], float& tot_e) {
  const unsigned eref = __builtin_amdgcn_readfirstlane(__float_as_uint(ps[0].x));
  const int e = (int)((eref >> 23) & 0xFFu) - 127;
  const float sc = __uint_as_float((unsigned)(127 - e) << 23);
#pragma unroll
  for (int mt = 0; mt < 4; ++mt) ps[mt] *= sc;
  tot_e += (float)e;
}

__device__ __forceinline__ float exp2i(int d) {  // 2^d for d in [-126, 127]
  return (d <= -127) ? 0.f : __uint_as_float((unsigned)(127 + d) << 23);
}

// ---------- chunk kernel: 512 threads = 2 chunks x 4 waves ----------
template <bool F32>
__global__ __launch_bounds__(512) void chunk_kernel(
    const char* __restrict__ eu, const float* __restrict__ trans,
    const int* __restrict__ lengths, char* __restrict__ scr, int scrStride) {
  constexpr int RB = F32 ? 256 : 128;  // LDS row bytes
  constexpr int SEG = RB / 8;          // per-thread segment bytes
  constexpr int STG = 32 * RB;         // LDS stage bytes

  const int b = blockIdx.x >> 2;
  const int cc = blockIdx.x & 3;
  const int len = lengths[b];
  if (2 * cc * kL >= len) return;  // both halves inactive (block-uniform)

  const int half = threadIdx.x >> 8;
  const int t8 = threadIdx.x & 255;
  const int lane = t8 & 63;
  const int w = t8 >> 6;
  const int col = lane & 15;
  const int q4 = lane >> 4;

  const int c = 2 * cc + half;
  const int start = c * kL;
  int steps = len - start;
  steps = steps < 0 ? 0 : (steps > kL ? kL : steps);

  __shared__ __align__(16) char smem[2][2][STG];  // [half][buf][stage]

  // Static A-fragments, psi-permuted K (verified rounds 2-6).
  bf16x8 af[4][2];
#pragma unroll
  for (int mt = 0; mt < 4; ++mt) {
#pragma unroll
    for (int kc = 0; kc < 2; ++kc) {
      union { unsigned u[4]; bf16x8 s; } fr;
#pragma unroll
      for (int jp = 0; jp < 4; ++jp) {
        const int j0 = 2 * jp, j1 = 2 * jp + 1;
        const int k0 = (2 * kc + (j0 >> 2)) * 16 + q4 * 4 + (j0 & 3);
        const int k1 = (2 * kc + (j1 >> 2)) * 16 + q4 * 4 + (j1 & 3);
        unsigned e0 = __float_as_uint(__expf(trans[(mt * 16 + col) * kN + k0])) + 0x8000u;
        unsigned e1 = __float_as_uint(__expf(trans[(mt * 16 + col) * kN + k1])) + 0x8000u;
        fr.u[jp] = __builtin_amdgcn_perm(e1, e0, 0x07060302u);
      }
      af[mt][kc] = fr.s;
    }
  }

  // Acc = identity columns; this wave owns columns w*16..w*16+15.
  const int mycol = w * 16 + col;
  f32x4 ps[4];
#pragma unroll
  for (int mt = 0; mt < 4; ++mt) {
    const int rb = mt * 16 + q4 * 4;
    f32x4 v;
    v.x = (rb + 0 == mycol) ? 1.f : 0.f;
    v.y = (rb + 1 == mycol) ? 1.f : 0.f;
    v.z = (rb + 2 == mycol) ? 1.f : 0.f;
    v.w = (rb + 3 == mycol) ? 1.f : 0.f;
    ps[mt] = v;
  }

  // Staging geometry. eu rows are 256 B (f32 full row / bf16 in lower 128 B).
  const char* gblk = eu + (size_t)(b * kT + start) * 256;
  const size_t gOff = (size_t)(t8 >> 3) * 256 + (size_t)(t8 & 7) * SEG;
  const size_t lOff = (size_t)(t8 >> 3) * RB + (size_t)(t8 & 7) * SEG;

  // Preload stage 0.
  {
    uint4 va = *(const uint4*)(gblk + gOff);
    uint4 vb;
    if constexpr (F32) vb = *(const uint4*)(gblk + gOff + 16);
    *(uint4*)(&smem[half][0][0] + lOff) = va;
    if constexpr (F32) *(uint4*)(&smem[half][0][0] + lOff + 16) = vb;
  }
  __syncthreads();

  float tot_e = 0.0f;
  for (int s = 0; s < 8; ++s) {  // fixed cadence: 8 stages x 32 steps
    uint4 va, vb;
    const bool more = (s < 7);
    if (more) {
      const char* g = gblk + (size_t)(s + 1) * 8192 + gOff;
      va = *(const uint4*)g;
      if constexpr (F32) vb = *(const uint4*)(g + 16);
    }

    int ns = steps - s * 32;
    ns = ns < 0 ? 0 : (ns > 32 ? 32 : ns);
    const char* lb = &smem[half][s & 1][0] + q4 * (RB / 4);
    if (ns == 32) {
#pragma unroll
      for (int g = 0; g < 8; ++g) {
        step_lds<F32>(ps, af, lb + (g * 4 + 0) * RB);
        step_lds<F32>(ps, af, lb + (g * 4 + 1) * RB);
        step_lds<F32>(ps, af, lb + (g * 4 + 2) * RB);
        step_lds<F32>(ps, af, lb + (g * 4 + 3) * RB);
        renorm(ps, tot_e);
      }
    } else {
      for (int i = 0; i < ns; ++i) {
        step_lds<F32>(ps, af, lb + (size_t)i * RB);
        if ((i & 3) == 3) renorm(ps, tot_e);
      }
    }

    if (more) {
      char* l = &smem[half][(s + 1) & 1][0] + lOff;
      *(uint4*)l = va;
      if constexpr (F32) *(uint4*)(l + 16) = vb;
    }
    __syncthreads();
  }

  if (steps > 0) {
    // Store 64x16 tile, column-major flat index F = tile*1024 + col*64 + row,
    // mapped to scratch slots of 32 floats with byte stride scrStride.
    const long tileIdx = ((long)b * kC + c) * 4 + w;
#pragma unroll
    for (int mt = 0; mt < 4; ++mt) {
      const long slot = tileIdx * 32 + col * 2 + (mt >> 1);
      char* addr = scr + slot * (long)scrStride + ((mt & 1) * 16 + q4 * 4) * 4;
      *(f32x4*)addr = ps[mt];
    }
    if (lane == 0) {
      const long F = kTileFloats + tileIdx;
      *(float*)(scr + (F >> 5) * (long)scrStride + (F & 31) * 4) = tot_e;
    }
  }
}

// ---------- combine: per batch, chain the chunk matrices (one wave) ----------
__global__ __launch_bounds__(64) void combine_kernel(
    const char* __restrict__ scr, int scrStride, const float* __restrict__ trans,
    const int* __restrict__ lengths, float* __restrict__ out) {
  const int b = blockIdx.x;
  const int j = threadIdx.x;
  const int len = lengths[b];

#define LDS_SCR(F) (*(const float*)(scr + ((long)(F) >> 5) * (long)scrStride + ((F) & 31) * 4))

  // alpha after chunk 0 = column kStart of chunk-0 matrix (wave 0's tile).
  const long t0 = (long)b * kC * 4;
  float a = LDS_SCR(t0 * 1024 + kStart * 64 + j);
  float totE = LDS_SCR(kTileFloats + t0);

  for (int c = 1; c < kC; ++c) {
    if (c * kL >= len) break;  // chunks are contiguous-active
    const long tb = ((long)b * kC + c) * 4;
    float s0 = 0.f, s1 = 0.f, s2 = 0.f, s3 = 0.f;
#pragma unroll
    for (int k16 = 0; k16 < 16; ++k16) {
      const float a0 = __int_as_float(__builtin_amdgcn_readlane(__float_as_int(a), k16));
      const float a1 = __int_as_float(__builtin_amdgcn_readlane(__float_as_int(a), 16 + k16));
      const float a2 = __int_as_float(__builtin_amdgcn_readlane(__float_as_int(a), 32 + k16));
      const float a3 = __int_as_float(__builtin_amdgcn_readlane(__float_as_int(a), 48 + k16));
      s0 = fmaf(LDS_SCR((tb + 0) * 1024 + k16 * 64 + j), a0, s0);
      s1 = fmaf(LDS_SCR((tb + 1) * 1024 + k16 * 64 + j), a1, s1);
      s2 = fmaf(LDS_SCR((tb + 2) * 1024 + k16 * 64 + j), a2, s2);
      s3 = fmaf(LDS_SCR((tb + 3) * 1024 + k16 * 64 + j), a3, s3);
    }
    const float e0 = LDS_SCR(kTileFloats + tb + 0);
    const float e1 = LDS_SCR(kTileFloats + tb + 1);
    const float e2 = LDS_SCR(kTileFloats + tb + 2);
    const float e3 = LDS_SCR(kTileFloats + tb + 3);
    const float em = fmaxf(fmaxf(e0, e1), fmaxf(e2, e3));
    a = s0 * exp2i((int)(e0 - em)) + s1 * exp2i((int)(e1 - em)) +
        s2 * exp2i((int)(e2 - em)) + s3 * exp2i((int)(e3 - em));
    totE += em;

    // renorm alpha (exact power of 2 from the wave max)
    float m = a;
#pragma unroll
    for (int mask = 1; mask < 64; mask <<= 1) m = fmaxf(m, __shfl_xor(m, mask));
    const int e = (int)((__float_as_uint(m) >> 23) & 0xFFu) - 127;
    a *= exp2i(-e);
    totE += (float)e;
  }

  float term = a * __expf(trans[kEnd * kN + j]);
#pragma unroll
  for (int mask = 1; mask < 64; mask <<= 1) term += __shfl_xor(term, mask);

  if (j == 0) out[b] = totE * 0.69314718055994530942f + logf(term);
#undef LDS_SCR
}

extern "C" void kernel_launch(void* const* d_in, const int* in_sizes, int n_in,
                              void* d_out, int out_size, void* d_ws, size_t ws_size,
                              hipStream_t stream) {
  const float* unary = (const float*)d_in[0];  // [B, T, N] fp32, 128 MiB
  const float* trans = (const float*)d_in[1];  // [N, N] fp32
  const int* lengths = (const int*)d_in[2];    // [B] int32
  float* out = (float*)d_out;                  // [B] fp32

  const size_t scrBytes = (size_t)(kTileFloats + kNumTiles) * 4;  // ~33.6 MB

  if (ws_size >= scrBytes) {
    // Primary: f32 eu swizzled in-place over d_in[0]; tiles in workspace.
    exp_swizzle_f32<<<dim3(4096), dim3(256), 0, stream>>>((float*)d_in[0]);
    chunk_kernel<true><<<dim3(kB * kC / 2), dim3(512), 0, stream>>>(
        (const char*)d_in[0], trans, lengths, (char*)d_ws, 128);
    combine_kernel<<<dim3(kB), dim3(64), 0, stream>>>((const char*)d_ws, 128,
                                                      trans, lengths, out);
  } else {
    // Fallback: bf16 eu in lower 128 B of each 256-B row of d_in[0]; tiles
    // in the upper 128 B halves (byte-disjoint; harness restores inputs).
    exp_swizzle_bf16<<<dim3(4096), dim3(256), 0, stream>>>(unary, (char*)d_in[0]);
    chunk_kernel<false><<<dim3(kB * kC / 2), dim3(512), 0, stream>>>(
        (const char*)d_in[0], trans, lengths, (char*)d_in[0] + 128, 256);
    combine_kernel<<<dim3(kB), dim3(64), 0, stream>>>((const char*)d_in[0] + 128,
                                                      256, trans, lengths, out);
  }
}